// Round 3
// baseline (218.425 us; speedup 1.0000x reference)
//
#include <hip/hip_runtime.h>
#include <hip/hip_bf16.h>
#include <cstdint>

// CIN layer chain: B=1024, F0=32, EMB=64, layer sizes 128/128/128.
// cur[b,k,e] = sum_{i,j} x[b,i,e] * h[b,j,e] * W[i*fi+j, k]
// Per batch: C(128 x 64) = W^T (128 x fan_in) @ Z (fan_in x 64),
//   Z[(i,j),e] = x[b,i,e]*h[b,j,e]  (built on the fly in B-fragments).

typedef _Float16 half8  __attribute__((ext_vector_type(8)));
typedef _Float16 half4_ __attribute__((ext_vector_type(4)));
typedef _Float16 half2_ __attribute__((ext_vector_type(2)));
typedef float    f32x4  __attribute__((ext_vector_type(4)));

__device__ __forceinline__ void load_lds16(const void* g, void* l) {
    __builtin_amdgcn_global_load_lds(
        reinterpret_cast<const __attribute__((address_space(1))) unsigned*>(
            reinterpret_cast<uintptr_t>(g)),
        reinterpret_cast<__attribute__((address_space(3))) unsigned*>(
            reinterpret_cast<uintptr_t>(l)),
        16, 0, 0);
}

// Pack W (fan_in,128) f32 -> chunked f16 Wt[c][m][kk] = W[c*32+kk][m]
// (exactly the LDS A-tile layout, so staging is one contiguous 8 KB read).
__global__ void pack_w(const float* __restrict__ W, _Float16* __restrict__ Wt)
{
    __shared__ _Float16 ldsT[128 * 33];
    const int c = blockIdx.x, t = threadIdx.x;
    for (int p = t; p < 32 * 128; p += 256) {
        int kk = p >> 7, m = p & 127;
        ldsT[m * 33 + kk] = (_Float16)W[(size_t)(c * 32 + kk) * 128 + m];
    }
    __syncthreads();
    int m = t >> 1, kk0 = (t & 1) * 16;
    half8 v0, v1;
#pragma unroll
    for (int i = 0; i < 8; ++i) {
        v0[i] = ldsT[m * 33 + kk0 + i];
        v1[i] = ldsT[m * 33 + kk0 + 8 + i];
    }
    // chunk base c*4096 halves; thread writes halves [t*16, t*16+16)
    *(half8*)(Wt + (size_t)c * 4096 + t * 16)     = v0;
    *(half8*)(Wt + (size_t)c * 4096 + t * 16 + 8) = v1;
}

// One CIN layer. Block = 2 batches, 256 threads (4 waves), tile M=128 x N=128.
// Wave w: m0=(w&1)*64 (k_out range), bb=w>>1 (which batch). 64x64 C tile/wave.
__global__ __launch_bounds__(256, 2)
void cin_layer(const float* __restrict__ x,         // (1024,32,64) f32
               const _Float16* __restrict__ h_in,   // (B,64,64) [b][e][j] f16, null => use x (fi=32)
               const _Float16* __restrict__ Wt,     // chunked [c][128][32] f16
               const float* __restrict__ bias,      // (128) f32
               _Float16* __restrict__ h_out,        // (B,64,64) [b][e][j] f16 or null
               float* __restrict__ out,             // (1024,256) f32
               int fi, int lfi, int nchunks, int direct_m0, int out_base)
{
    __shared__ alignas(16) _Float16 sW[128 * 32];      // 8 KB  W chunk [m][kk]
    __shared__ alignas(16) _Float16 sH[2 * 64 * 64];   // 16 KB hT [bb][e*fi+j]
    __shared__ alignas(16) unsigned sX[2 * 32 * 64];   // 16 KB x dup-f16-pair [bb][i*64+e]

    const int t    = threadIdx.x;
    const int lane = t & 63;
    const int w    = t >> 6;
    const int lr   = lane & 15;
    const int q    = lane >> 4;
    const int b0   = blockIdx.x * 2;

    // Build packed x (duplicated f16 pair -> one v_pk_mul_f16 operand).
    for (int p = t; p < 2 * 2048; p += 256) {
        float v = x[(size_t)(b0 + (p >> 11)) * 2048 + (p & 2047)];
        _Float16 hv = (_Float16)v;
        unsigned short us = __builtin_bit_cast(unsigned short, hv);
        sX[p] = (unsigned)us * 0x10001u;
    }
    // Stage hidden (transposed [e][j]) into LDS.
    if (h_in) {
        const char* src = (const char*)(h_in + (size_t)b0 * 4096);
        char* dst = (char*)sH;
#pragma unroll
        for (int r = 0; r < 4; ++r)
            load_lds16(src + r * 4096 + t * 16, dst + r * 4096 + t * 16);
    } else {
        // layer 0: hidden = x, fi = 32
        for (int p = t; p < 2 * 2048; p += 256) {
            int bb = p >> 11, idx = p & 2047;
            int j = idx >> 6, e = idx & 63;
            sH[bb * 2048 + e * 32 + j] = (_Float16)x[(size_t)(b0 + bb) * 2048 + idx];
        }
    }

    const int m0 = (w & 1) * 64;
    const int bb = w >> 1;

    // A-tile pointer MUST include the wave's row offset m0 (R2 bugfix):
    const _Float16* aP = sW + (m0 + lr) * 32 + q * 8;           // + mt*512
    const _Float16* hP = sH + bb * (fi << 6) + lr * fi + q * 8; // + nt*16*fi + j0
    const unsigned* xP = sX + (bb << 11) + lr;                  // + i*64 + nt*16

    f32x4 acc[4][4] = {};

    for (int c = 0; c < nchunks; ++c) {
        // Stage W chunk c (8 KB) via async global->LDS, width 16.
        const char* wsrc = (const char*)Wt + (size_t)c * 8192 + (size_t)t * 16;
        char* wdst = (char*)sW + (size_t)t * 16;
        load_lds16(wsrc, wdst);
        load_lds16(wsrc + 4096, wdst + 4096);
        __syncthreads();

        const int k0 = c << 5;
        const int i  = k0 >> lfi;       // which x-field this chunk belongs to
        const int j0 = k0 & (fi - 1);   // j offset within hidden

        half8 af[4];
#pragma unroll
        for (int mt = 0; mt < 4; ++mt)
            af[mt] = *(const half8*)(aP + mt * 512);

        half8 bf[4];
#pragma unroll
        for (int nt = 0; nt < 4; ++nt) {
            half8 hv = *(const half8*)(hP + nt * (fi << 4) + j0);
            half2_ xv = __builtin_bit_cast(half2_, xP[(i << 6) + (nt << 4)]);
            half8 xv8 = __builtin_shufflevector(xv, xv, 0, 1, 0, 1, 0, 1, 0, 1);
            bf[nt] = hv * xv8;   // elementwise, no punning
        }
#pragma unroll
        for (int mt = 0; mt < 4; ++mt)
#pragma unroll
            for (int nt = 0; nt < 4; ++nt)
                acc[mt][nt] = __builtin_amdgcn_mfma_f32_16x16x32_f16(
                    af[mt], bf[nt], acc[mt][nt], 0, 0, 0);
        __syncthreads();
    }

    const int batch = b0 + bb;

    // bias (zeros in this problem, but apply per spec)
#pragma unroll
    for (int mt = 0; mt < 4; ++mt)
#pragma unroll
        for (int r = 0; r < 4; ++r) {
            float bv = bias[m0 + mt * 16 + q * 4 + r];
#pragma unroll
            for (int nt = 0; nt < 4; ++nt) acc[mt][nt][r] += bv;
        }

    if (h_out != nullptr && m0 == 0) {
        // hidden half: write cur[b][j=m][e] transposed -> h_out[b][e][j] (f16)
#pragma unroll
        for (int mt = 0; mt < 4; ++mt)
#pragma unroll
            for (int nt = 0; nt < 4; ++nt) {
                int e = nt * 16 + lr;
                int j = mt * 16 + q * 4;
                half4_ vh;
#pragma unroll
                for (int r = 0; r < 4; ++r) vh[r] = (_Float16)acc[mt][nt][r];
                *(half4_*)(h_out + (size_t)batch * 4096 + e * 64 + j) = vh;
            }
    } else {
        // direct half: reduce over e (all 64 n of this wave) and write out
#pragma unroll
        for (int mt = 0; mt < 4; ++mt) {
            f32x4 s = acc[mt][0] + acc[mt][1] + acc[mt][2] + acc[mt][3];
#pragma unroll
            for (int r = 0; r < 4; ++r) {
                float v = s[r];
                v += __shfl_xor(v, 1);
                v += __shfl_xor(v, 2);
                v += __shfl_xor(v, 4);
                v += __shfl_xor(v, 8);
                if (lr == 0) {
                    int m = m0 + mt * 16 + q * 4 + r;
                    out[(size_t)batch * 256 + out_base + (m - direct_m0)] = v;
                }
            }
        }
    }
}

extern "C" void kernel_launch(void* const* d_in, const int* in_sizes, int n_in,
                              void* d_out, int out_size, void* d_ws, size_t ws_size,
                              hipStream_t stream)
{
    const float* x  = (const float*)d_in[0];
    const float* W0 = (const float*)d_in[1];
    const float* b0 = (const float*)d_in[2];
    const float* W1 = (const float*)d_in[3];
    const float* b1 = (const float*)d_in[4];
    const float* W2 = (const float*)d_in[5];
    const float* b2 = (const float*)d_in[6];
    float* out = (float*)d_out;

    char* ws = (char*)d_ws;
    _Float16* Wt0 = (_Float16*)(ws + 0);                      // 1024*128*2  = 256 KB
    _Float16* Wt1 = (_Float16*)(ws + 262144);                 // 2048*128*2  = 512 KB
    _Float16* Wt2 = (_Float16*)(ws + 786432);                 // 512 KB
    _Float16* h1  = (_Float16*)(ws + 1310720);                // 1024*64*64*2 = 8 MB
    _Float16* h2  = (_Float16*)(ws + 1310720 + 8388608);      // 8 MB
    (void)in_sizes; (void)n_in; (void)out_size; (void)ws_size;

    hipLaunchKernelGGL(pack_w, dim3(32), dim3(256), 0, stream, W0, Wt0);
    hipLaunchKernelGGL(pack_w, dim3(64), dim3(256), 0, stream, W1, Wt1);
    hipLaunchKernelGGL(pack_w, dim3(64), dim3(256), 0, stream, W2, Wt2);

    // layer 0: fi=32 (hidden = x), direct rows m in [64,128) -> out cols 0..63
    hipLaunchKernelGGL(cin_layer, dim3(512), dim3(256), 0, stream,
                       x, (const _Float16*)nullptr, Wt0, b0, h1, out,
                       32, 5, 32, 64, 0);
    // layer 1: fi=64, direct rows -> out cols 64..127
    hipLaunchKernelGGL(cin_layer, dim3(512), dim3(256), 0, stream,
                       x, (const _Float16*)h1, Wt1, b1, h2, out,
                       64, 6, 64, 64, 64);
    // layer 2: fi=64, all 128 rows direct -> out cols 128..255
    hipLaunchKernelGGL(cin_layer, dim3(512), dim3(256), 0, stream,
                       x, (const _Float16*)h2, Wt2, b2, (_Float16*)nullptr, out,
                       64, 6, 64, 0, 128);
}

// Round 4
// 179.869 us; speedup vs baseline: 1.2144x; 1.2144x over previous
//
#include <hip/hip_runtime.h>
#include <hip/hip_bf16.h>
#include <cstdint>

// CIN layer chain: B=1024, F0=32, EMB=64, layer sizes 128/128/128.
// cur[b,k,e] = sum_{i,j} x[b,i,e] * h[b,j,e] * W[i*fi+j, k]
// Per batch: C(128 x 64) = W^T (128 x fan_in) @ Z (fan_in x 64),
//   Z[(i,j),e] = x[b,i,e]*h[b,j,e]  (built on the fly in B-fragments).
//
// R4 structure: 1 batch/block, 128 threads (2 m-half waves), grid 1024
// (4 blocks/CU), 2-chunk unroll per barrier, sH padded pitch 72/40 to
// kill the 2x bank aliasing seen in R3 (SQ_LDS_BANK_CONFLICT 8.4M).

typedef _Float16 half8  __attribute__((ext_vector_type(8)));
typedef _Float16 half4_ __attribute__((ext_vector_type(4)));
typedef _Float16 half2_ __attribute__((ext_vector_type(2)));
typedef float    f32x4  __attribute__((ext_vector_type(4)));

__device__ __forceinline__ void load_lds16(const void* g, void* l) {
    __builtin_amdgcn_global_load_lds(
        reinterpret_cast<const __attribute__((address_space(1))) unsigned*>(
            reinterpret_cast<uintptr_t>(g)),
        reinterpret_cast<__attribute__((address_space(3))) unsigned*>(
            reinterpret_cast<uintptr_t>(l)),
        16, 0, 0);
}

__device__ __forceinline__ unsigned dupf16(float v) {
    unsigned short us = __builtin_bit_cast(unsigned short, (_Float16)v);
    return (unsigned)us * 0x10001u;
}

// Pack W (fan_in,128) f32 -> chunked f16 Wt[c][m][kk] = W[c*32+kk][m]
// (exactly the LDS A-tile layout, so staging is one contiguous 8 KB read).
__global__ void pack_w(const float* __restrict__ W, _Float16* __restrict__ Wt)
{
    __shared__ _Float16 ldsT[128 * 33];
    const int c = blockIdx.x, t = threadIdx.x;
    for (int p = t; p < 32 * 128; p += 256) {
        int kk = p >> 7, m = p & 127;
        ldsT[m * 33 + kk] = (_Float16)W[(size_t)(c * 32 + kk) * 128 + m];
    }
    __syncthreads();
    int m = t >> 1, kk0 = (t & 1) * 16;
    half8 v0, v1;
#pragma unroll
    for (int i = 0; i < 8; ++i) {
        v0[i] = ldsT[m * 33 + kk0 + i];
        v1[i] = ldsT[m * 33 + kk0 + 8 + i];
    }
    *(half8*)(Wt + (size_t)c * 4096 + t * 16)     = v0;
    *(half8*)(Wt + (size_t)c * 4096 + t * 16 + 8) = v1;
}

// One CIN layer. Block = 1 batch, 128 threads (2 waves). Wave w: m0=w*64.
__global__ __launch_bounds__(128, 2)
void cin_layer(const float* __restrict__ x,         // (1024,32,64) f32
               const _Float16* __restrict__ h_in,   // (B,64,72) padded image, null => use x
               const _Float16* __restrict__ Wt,     // chunked [c][128][32] f16
               const float* __restrict__ bias,      // (128) f32
               _Float16* __restrict__ h_out,        // (B,64,72) padded image or null
               float* __restrict__ out,             // (1024,256) f32
               int fi, int lfi, int nchunks, int ph, int direct_m0, int out_base)
{
    __shared__ alignas(16) _Float16 sW[2 * 4096];   // 16 KB: 2 W chunks [cc][m][kk]
    __shared__ alignas(16) _Float16 sH[64 * 72];    // 9216 B: hT [e*ph + j]
    __shared__ alignas(16) unsigned sX[2048];       // 8 KB: x dup-f16-pair [i*64+e]

    const int t    = threadIdx.x;
    const int lane = t & 63;
    const int w    = t >> 6;
    const int lr   = lane & 15;
    const int q    = lane >> 4;
    const int b    = blockIdx.x;

    // Build packed x (dup f16 pair -> one v_pk_mul_f16 operand), float4 loads.
    {
        const float4* xv = (const float4*)(x + (size_t)b * 2048);
#pragma unroll
        for (int s = 0; s < 4; ++s) {
            int p4 = t + s * 128;
            float4 v = xv[p4];
            uint4 d;
            d.x = dupf16(v.x); d.y = dupf16(v.y);
            d.z = dupf16(v.z); d.w = dupf16(v.w);
            *(uint4*)(sX + p4 * 4) = d;
            if (!h_in) {
                // layer 0: hidden = x; build hT [e][j], pitch ph=40
                int p0 = p4 * 4;
                int i = p0 >> 6, e0 = p0 & 63;
                sH[(e0 + 0) * 40 + i] = (_Float16)v.x;
                sH[(e0 + 1) * 40 + i] = (_Float16)v.y;
                sH[(e0 + 2) * 40 + i] = (_Float16)v.z;
                sH[(e0 + 3) * 40 + i] = (_Float16)v.w;
            }
        }
    }
    if (h_in) {
        // stage padded hT image (9216 B) via async global->LDS
        const char* src = (const char*)(h_in + (size_t)b * 4608);
        char* dst = (char*)sH;
        for (int off = t * 16; off < 9216; off += 2048)
            load_lds16(src + off, dst + off);
    }

    const int m0 = w * 64;

    const _Float16* aPb = sW + (m0 + lr) * 32 + q * 8;   // + cc*4096 + mt*512
    const _Float16* hP  = sH + lr * ph + q * 8;          // + nt*16*ph + j0
    const unsigned* xP  = sX + lr;                       // + i*64 + nt*16

    f32x4 acc[4][4] = {};

    const int niter = nchunks >> 1;
    for (int it = 0; it < niter; ++it) {
        // Stage 2 W chunks (16 KB) via async global->LDS, width 16.
        const char* wsrc = (const char*)Wt + (size_t)it * 16384 + (size_t)t * 16;
        char* wdst = (char*)sW + (size_t)t * 16;
#pragma unroll
        for (int s = 0; s < 8; ++s)
            load_lds16(wsrc + s * 2048, wdst + s * 2048);
        __syncthreads();

#pragma unroll
        for (int cc = 0; cc < 2; ++cc) {
            const int c  = it * 2 + cc;
            const int k0 = c << 5;
            const int i  = k0 >> lfi;       // which x-field this chunk covers
            const int j0 = k0 & (fi - 1);   // j offset within hidden

            const _Float16* aP = aPb + cc * 4096;
            half8 af[4];
#pragma unroll
            for (int mt = 0; mt < 4; ++mt)
                af[mt] = *(const half8*)(aP + mt * 512);

            half8 bf[4];
#pragma unroll
            for (int nt = 0; nt < 4; ++nt) {
                half8 hv = *(const half8*)(hP + nt * (ph << 4) + j0);
                half2_ xv = __builtin_bit_cast(half2_, xP[(i << 6) + (nt << 4)]);
                half8 xv8 = __builtin_shufflevector(xv, xv, 0, 1, 0, 1, 0, 1, 0, 1);
                bf[nt] = hv * xv8;
            }
#pragma unroll
            for (int mt = 0; mt < 4; ++mt)
#pragma unroll
                for (int nt = 0; nt < 4; ++nt)
                    acc[mt][nt] = __builtin_amdgcn_mfma_f32_16x16x32_f16(
                        af[mt], bf[nt], acc[mt][nt], 0, 0, 0);
        }
        __syncthreads();
    }

    // bias (zeros in this problem, but apply per spec)
#pragma unroll
    for (int mt = 0; mt < 4; ++mt)
#pragma unroll
        for (int r = 0; r < 4; ++r) {
            float bv = bias[m0 + mt * 16 + q * 4 + r];
#pragma unroll
            for (int nt = 0; nt < 4; ++nt) acc[mt][nt][r] += bv;
        }

    if (h_out != nullptr && m0 == 0) {
        // hidden half: write cur[b][j=m][e] transposed into padded image
        // h_out[b][e*72 + j] (f16); C/D map: col=lr, row=q*4+r (m89).
#pragma unroll
        for (int mt = 0; mt < 4; ++mt)
#pragma unroll
            for (int nt = 0; nt < 4; ++nt) {
                int e = nt * 16 + lr;
                int j = mt * 16 + q * 4;
                half4_ vh;
#pragma unroll
                for (int r = 0; r < 4; ++r) vh[r] = (_Float16)acc[mt][nt][r];
                *(half4_*)(h_out + (size_t)b * 4608 + e * 72 + j) = vh;
            }
    } else {
        // direct half: reduce over e and write out
#pragma unroll
        for (int mt = 0; mt < 4; ++mt) {
            f32x4 s = acc[mt][0] + acc[mt][1] + acc[mt][2] + acc[mt][3];
#pragma unroll
            for (int r = 0; r < 4; ++r) {
                float v = s[r];
                v += __shfl_xor(v, 1);
                v += __shfl_xor(v, 2);
                v += __shfl_xor(v, 4);
                v += __shfl_xor(v, 8);
                if (lr == 0) {
                    int m = m0 + mt * 16 + q * 4 + r;
                    out[(size_t)b * 256 + out_base + (m - direct_m0)] = v;
                }
            }
        }
    }
}

extern "C" void kernel_launch(void* const* d_in, const int* in_sizes, int n_in,
                              void* d_out, int out_size, void* d_ws, size_t ws_size,
                              hipStream_t stream)
{
    const float* x  = (const float*)d_in[0];
    const float* W0 = (const float*)d_in[1];
    const float* b0 = (const float*)d_in[2];
    const float* W1 = (const float*)d_in[3];
    const float* b1 = (const float*)d_in[4];
    const float* W2 = (const float*)d_in[5];
    const float* b2 = (const float*)d_in[6];
    float* out = (float*)d_out;

    char* ws = (char*)d_ws;
    _Float16* Wt0 = (_Float16*)(ws + 0);                        // 256 KB
    _Float16* Wt1 = (_Float16*)(ws + 262144);                   // 512 KB
    _Float16* Wt2 = (_Float16*)(ws + 786432);                   // 512 KB
    _Float16* h1  = (_Float16*)(ws + 1310720);                  // 1024*4608*2 = 9 MB
    _Float16* h2  = (_Float16*)(ws + 1310720 + 9437184);        // 9 MB
    (void)in_sizes; (void)n_in; (void)out_size; (void)ws_size;

    hipLaunchKernelGGL(pack_w, dim3(32), dim3(256), 0, stream, W0, Wt0);
    hipLaunchKernelGGL(pack_w, dim3(64), dim3(256), 0, stream, W1, Wt1);
    hipLaunchKernelGGL(pack_w, dim3(64), dim3(256), 0, stream, W2, Wt2);

    // layer 0: fi=32 (hidden = x), direct rows m in [64,128) -> out cols 0..63
    hipLaunchKernelGGL(cin_layer, dim3(1024), dim3(128), 0, stream,
                       x, (const _Float16*)nullptr, Wt0, b0, h1, out,
                       32, 5, 32, 40, 64, 0);
    // layer 1: fi=64, direct rows -> out cols 64..127
    hipLaunchKernelGGL(cin_layer, dim3(1024), dim3(128), 0, stream,
                       x, (const _Float16*)h1, Wt1, b1, h2, out,
                       64, 6, 64, 72, 64, 64);
    // layer 2: fi=64, all 128 rows direct -> out cols 128..255
    hipLaunchKernelGGL(cin_layer, dim3(1024), dim3(128), 0, stream,
                       x, (const _Float16*)h2, Wt2, b2, (_Float16*)nullptr, out,
                       64, 6, 64, 72, 0, 128);
}